// Round 1
// baseline (2511.502 us; speedup 1.0000x reference)
//
#include <hip/hip_runtime.h>
#include <math.h>

#define F_IN   500
#define H_DIM  64
#define C_DIM  40
#define K_STEPS 10
#define ALPHA  0.1f
#define CB     5     // channel blocks
#define CBW    8     // floats per block (32 B/node: one block = 3.2 MB, fits 4 MiB per-XCD L2)

typedef float vf4 __attribute__((ext_vector_type(4)));

// ---------------------------------------------------------------------------
// Fused MLP GEMM: h0 = relu(x@W1+b1)@W2+b2, one 64-row tile per block.
// Output now written in channel-blocked T layout [CB][N][CBW].
// NOTE (next round): 1.6e7 LDS bank conflicts come from the scalar transposed
// xs store (8-way: 4*LDA1 % 32 == 16); plus MfmaUtil=0 -> split-bf16 MFMA.
// ---------------------------------------------------------------------------
#define LDA1 68
__global__ __launch_bounds__(256) void mlp_gemm(
    const float* __restrict__ x, const float* __restrict__ W1,
    const float* __restrict__ b1, const float* __restrict__ W2,
    const float* __restrict__ b2, float* __restrict__ h0,
    float* __restrict__ hA, int N)
{
    __shared__ float smem[64 * LDA1 * 2 + H_DIM * C_DIM];
    float* xs  = smem;
    float* ws  = smem + 64 * LDA1;
    float* w2s = smem + 2 * 64 * LDA1;

    const int t    = threadIdx.x;
    const int row0 = blockIdx.x * 64;
    const int tx   = t & 15;
    const int ty   = t >> 4;

    for (int i = t; i < H_DIM * C_DIM; i += 256) w2s[i] = W2[i];

    const float4 b1v = *(const float4*)&b1[tx * 4];

    float acc[4][4];
    #pragma unroll
    for (int i = 0; i < 4; ++i)
        #pragma unroll
        for (int j = 0; j < 4; ++j) acc[i][j] = 0.f;

    for (int k0 = 0; k0 < F_IN; k0 += 64) {
        __syncthreads();
        #pragma unroll
        for (int i = 0; i < 4; ++i) {
            int f  = t + i * 256;
            int r  = f >> 4;
            int c4 = (f & 15) << 2;
            int grow = row0 + r, gk = k0 + c4;
            float4 v = make_float4(0.f, 0.f, 0.f, 0.f);
            if (grow < N && gk < F_IN)
                v = *(const float4*)&x[(long long)grow * F_IN + gk];
            xs[(c4 + 0) * LDA1 + r] = v.x;
            xs[(c4 + 1) * LDA1 + r] = v.y;
            xs[(c4 + 2) * LDA1 + r] = v.z;
            xs[(c4 + 3) * LDA1 + r] = v.w;
        }
        #pragma unroll
        for (int i = 0; i < 4; ++i) {
            int f  = t + i * 256;
            int r  = f >> 4;
            int c4 = (f & 15) << 2;
            int gk = k0 + r;
            float4 v = make_float4(0.f, 0.f, 0.f, 0.f);
            if (gk < F_IN)
                v = *(const float4*)&W1[(long long)gk * H_DIM + c4];
            *(float4*)&ws[r * LDA1 + c4] = v;
        }
        __syncthreads();
        #pragma unroll 8
        for (int kk = 0; kk < 64; ++kk) {
            float4 a4 = *(const float4*)&xs[kk * LDA1 + ty * 4];
            float4 b4 = *(const float4*)&ws[kk * LDA1 + tx * 4];
            const float av[4] = {a4.x, a4.y, a4.z, a4.w};
            const float bv[4] = {b4.x, b4.y, b4.z, b4.w};
            #pragma unroll
            for (int i = 0; i < 4; ++i)
                #pragma unroll
                for (int j = 0; j < 4; ++j)
                    acc[i][j] = fmaf(av[i], bv[j], acc[i][j]);
        }
    }

    __syncthreads();
    #pragma unroll
    for (int i = 0; i < 4; ++i) {
        float4 hv;
        hv.x = fmaxf(acc[i][0] + b1v.x, 0.f);
        hv.y = fmaxf(acc[i][1] + b1v.y, 0.f);
        hv.z = fmaxf(acc[i][2] + b1v.z, 0.f);
        hv.w = fmaxf(acc[i][3] + b1v.w, 0.f);
        *(float4*)&xs[(ty * 4 + i) * LDA1 + tx * 4] = hv;
    }
    __syncthreads();

    for (int o = t; o < 64 * C_DIM; o += 256) {
        int r = o / C_DIM;
        int c = o - r * C_DIM;
        float s = b2[c];
        #pragma unroll 16
        for (int j = 0; j < H_DIM; ++j)
            s = fmaf(xs[r * LDA1 + j], w2s[j * C_DIM + c], s);
        int grow = row0 + r;
        if (grow < N) {
            // channel-blocked T layout: [c>>3][row][c&7]
            int idx = ((c >> 3) * N + grow) * CBW + (c & 7);
            h0[idx] = s;
            hA[idx] = s;
        }
    }
}

// ---------------------------------------------------------------------------
// Degree / normalization
// ---------------------------------------------------------------------------
__global__ void deg_init(float* __restrict__ deg, int N) {
    int i = blockIdx.x * 256 + threadIdx.x;
    if (i < N) deg[i] = 1.0f;               // self-loop
}

__global__ void deg_count(const int* __restrict__ dst, float* __restrict__ deg, int E) {
    int e = blockIdx.x * 256 + threadIdx.x;
    if (e < E) atomicAdd(&deg[dst[e]], 1.0f);
}

__global__ void dinv_kernel(float* __restrict__ deg, int* __restrict__ lengths, int N) {
    int i = blockIdx.x * 256 + threadIdx.x;
    if (i < N) {
        float d = deg[i];
        deg[i] = 1.0f / sqrtf(d);
        lengths[i] = (int)(d - 0.5f);
    }
}

// ---------------------------------------------------------------------------
// Exclusive prefix scan of row lengths -> row_ptr  (3-kernel block scan)
// ---------------------------------------------------------------------------
__global__ void scan1(const int* __restrict__ len, int* __restrict__ rp,
                      int* __restrict__ bsums, int N) {
    __shared__ int tmp[256];
    int tid = threadIdx.x;
    int gid = blockIdx.x * 256 + tid;
    int v = (gid < N) ? len[gid] : 0;
    tmp[tid] = v;
    __syncthreads();
    for (int off = 1; off < 256; off <<= 1) {
        int t = (tid >= off) ? tmp[tid - off] : 0;
        __syncthreads();
        tmp[tid] += t;
        __syncthreads();
    }
    if (gid < N) rp[gid] = tmp[tid] - v;
    if (tid == 255) bsums[blockIdx.x] = tmp[tid];
}

__global__ void scan2(int* __restrict__ bsums, int nb) {
    __shared__ int tmp[512];
    int tid = threadIdx.x;
    int v = (tid < nb) ? bsums[tid] : 0;
    tmp[tid] = v;
    __syncthreads();
    for (int off = 1; off < 512; off <<= 1) {
        int t = (tid >= off) ? tmp[tid - off] : 0;
        __syncthreads();
        tmp[tid] += t;
        __syncthreads();
    }
    if (tid < nb) bsums[tid] = tmp[tid] - v;
}

__global__ void scan3(int* __restrict__ rp, const int* __restrict__ bsums,
                      int* __restrict__ cursor, int N, int E) {
    int gid = blockIdx.x * 256 + threadIdx.x;
    if (gid < N) {
        int v = rp[gid] + bsums[blockIdx.x];
        rp[gid] = v;
        cursor[gid] = v;
    }
    if (gid == 0) rp[N] = E;
}

// ---------------------------------------------------------------------------
// CSR fill (direct scatter): earr[pos] = src | wq<<17,
// wq = round(dinv[src]*32767) (15-bit quantized, ~1e-4 rel err).
// ---------------------------------------------------------------------------
__global__ void csr_fill_direct(const int* __restrict__ src, const int* __restrict__ dst,
                                const float* __restrict__ dinv,
                                int* __restrict__ cursor, int* __restrict__ earr, int E) {
    int e = blockIdx.x * 256 + threadIdx.x;
    if (e >= E) return;
    int s = src[e];
    int d = dst[e];
    int pos = atomicAdd(&cursor[d], 1);
    unsigned wq = (unsigned)(dinv[s] * 32767.f + 0.5f);
    earr[pos] = (int)((unsigned)s | (wq << 17));
}

// ---------------------------------------------------------------------------
// PPR step v4: channel-blocked transposed state [CB][N][CBW].
// grid = (N/4, CB); for pass cb the 3.2 MB block is L2-resident per XCD
// (x-major dispatch keeps all CUs on the same cb at a time), so the random
// per-edge gathers hit L2 instead of Infinity Cache.
// Wave layout: 2 lanes per edge (float4 halves of the 32 B node record,
// same 64 B line -> 1 TA transaction/edge), 32 edges per load instruction.
// Streams (earr / h0 / hout) are nontemporal so they don't evict the block.
//   houtT[cb][i] = 0.9*dinv_i*(dinv_i*hinT[cb][i] + sum_e w_s*hinT[cb][s]) + 0.1*h0T[cb][i]
// ---------------------------------------------------------------------------
__global__ __launch_bounds__(256) void prop_t(
    const float* __restrict__ hin, const float* __restrict__ h0,
    const float* __restrict__ dinv, const int* __restrict__ rp,
    const int* __restrict__ earr,
    float* __restrict__ hout, int N)
{
    const int wave = threadIdx.x >> 6;
    const int lane = threadIdx.x & 63;
    const int row  = blockIdx.x * 4 + wave;
    if (row >= N) return;
    const int cb   = blockIdx.y;

    const int rs = rp[row];
    const int re = rp[row + 1];
    const float dr     = dinv[row];
    const float factor = (1.0f - ALPHA) * dr;
    const float invq   = 1.0f / 32767.f;

    const float* __restrict__ hb = hin + (size_t)cb * N * CBW;
    const int eslot = lane >> 1;          // edge slot within 32-edge group
    const int boff  = (lane & 1) << 2;    // channel half: float offset 0 or 4

    vf4 a0 = {0.f, 0.f, 0.f, 0.f};
    vf4 a1 = {0.f, 0.f, 0.f, 0.f};

    for (int base = rs; base < re; base += 64) {
        int p = 0;
        const int ee = base + lane;
        if (ee < re) p = __builtin_nontemporal_load(&earr[ee]);  // padded lanes: p=0 -> w=0
        const int cnt = re - base;
        {
            const unsigned up = (unsigned)__shfl(p, eslot);
            const int   s = (int)(up & 0x1FFFFu);
            const float w = (float)(up >> 17) * invq;
            const vf4 v = *(const vf4*)(hb + (s << 3) + boff);
            a0.x = fmaf(w, v.x, a0.x);
            a0.y = fmaf(w, v.y, a0.y);
            a0.z = fmaf(w, v.z, a0.z);
            a0.w = fmaf(w, v.w, a0.w);
        }
        if (cnt > 32) {
            const unsigned up = (unsigned)__shfl(p, 32 + eslot);
            const int   s = (int)(up & 0x1FFFFu);
            const float w = (float)(up >> 17) * invq;
            const vf4 v = *(const vf4*)(hb + (s << 3) + boff);
            a1.x = fmaf(w, v.x, a1.x);
            a1.y = fmaf(w, v.y, a1.y);
            a1.z = fmaf(w, v.z, a1.z);
            a1.w = fmaf(w, v.w, a1.w);
        }
    }

    vf4 acc = a0 + a1;
    // reduce over the 32 lane-pairs; parity (lane&1) classes stay separate
    #pragma unroll
    for (int off = 2; off <= 32; off <<= 1) {
        acc.x += __shfl_xor(acc.x, off);
        acc.y += __shfl_xor(acc.y, off);
        acc.z += __shfl_xor(acc.z, off);
        acc.w += __shfl_xor(acc.w, off);
    }

    if (lane < 2) {
        const int o = (cb * N + row) * CBW + (lane << 2);
        const vf4 hv  = *(const vf4*)(hin + o);                       // hot block, cached
        const vf4 h0v = __builtin_nontemporal_load((const vf4*)(h0 + o));
        vf4 r;
        r.x = fmaf(factor, acc.x + dr * hv.x, ALPHA * h0v.x);
        r.y = fmaf(factor, acc.y + dr * hv.y, ALPHA * h0v.y);
        r.z = fmaf(factor, acc.z + dr * hv.z, ALPHA * h0v.z);
        r.w = fmaf(factor, acc.w + dr * hv.w, ALPHA * h0v.w);
        __builtin_nontemporal_store(r, (vf4*)(hout + o));
    }
}

// ---------------------------------------------------------------------------
// Row-wise log_softmax over 40 channels, reading channel-blocked T layout
// ---------------------------------------------------------------------------
__global__ __launch_bounds__(256) void lsm_kernel(const float* __restrict__ hin,
                                                  float* __restrict__ out, int N) {
    const int wave = threadIdx.x >> 6;
    const int lane = threadIdx.x & 63;
    const int row  = blockIdx.x * 4 + wave;
    if (row >= N) return;

    float v = -INFINITY;
    if (lane < C_DIM)
        v = hin[((lane >> 3) * N + row) * CBW + (lane & 7)];
    float m = v;
    for (int off = 32; off; off >>= 1) m = fmaxf(m, __shfl_xor(m, off));
    float e = (lane < C_DIM) ? expf(v - m) : 0.f;
    float s = e;
    for (int off = 32; off; off >>= 1) s += __shfl_xor(s, off);
    if (lane < C_DIM) out[(long long)row * C_DIM + lane] = (v - m) - logf(s);
}

// ---------------------------------------------------------------------------
extern "C" void kernel_launch(void* const* d_in, const int* in_sizes, int n_in,
                              void* d_out, int out_size, void* d_ws, size_t ws_size,
                              hipStream_t stream) {
    const float* x  = (const float*)d_in[0];
    const float* W1 = (const float*)d_in[1];
    const float* b1 = (const float*)d_in[2];
    const float* W2 = (const float*)d_in[3];
    const float* b2 = (const float*)d_in[4];
    const int* ei = (const int*)d_in[5];   // int32 per harness contract

    const int N = in_sizes[0] / F_IN;          // 100000
    const int E = in_sizes[5] / 2;             // 3200000
    const int* src = ei;
    const int* dst = ei + E;
    float* out = (float*)d_out;

    char* w = (char*)d_ws;
    float* h0    = (float*)w;  w += (size_t)N * C_DIM * 4;   // 16 MB  (T layout [CB][N][CBW])
    float* hA    = (float*)w;  w += (size_t)N * C_DIM * 4;   // 16 MB  (T layout)
    float* dinv  = (float*)w;  w += (size_t)N * 4;           // deg -> dinv in place
    int*   rp    = (int*)w;    w += (size_t)(N + 1) * 4;
    int*   cursor= (int*)w;    w += (size_t)N * 4;           // lengths, then cursor
    int*   bsums = (int*)w;    w += (size_t)512 * 4;
    int*   earr  = (int*)w;    w += (size_t)E * 4;           // 12.8 MB packed edges

    const int nbN = (N + 255) / 256;
    const int nbE = (E + 255) / 256;
    const int nbRow = (N + 3) / 4;
    const int nbGemm = (N + 63) / 64;

    mlp_gemm<<<nbGemm, 256, 0, stream>>>(x, W1, b1, W2, b2, h0, hA, N);

    deg_init <<<nbN, 256, 0, stream>>>(dinv, N);
    deg_count<<<nbE, 256, 0, stream>>>(dst, dinv, E);
    dinv_kernel<<<nbN, 256, 0, stream>>>(dinv, cursor, N);

    scan1<<<nbN, 256, 0, stream>>>(cursor, rp, bsums, N);
    scan2<<<1, 512, 0, stream>>>(bsums, nbN);
    scan3<<<nbN, 256, 0, stream>>>(rp, bsums, cursor, N, E);

    csr_fill_direct<<<nbE, 256, 0, stream>>>(src, dst, dinv, cursor, earr, E);

    // ping-pong: hA (T) <-> out-as-scratch (T); after 10 steps result is in hA
    float* a = hA; float* b = out;
    dim3 pgrid(nbRow, CB);
    for (int k = 0; k < K_STEPS; ++k) {
        prop_t<<<pgrid, 256, 0, stream>>>(a, h0, dinv, rp, earr, b, N);
        float* t = a; a = b; b = t;
    }

    lsm_kernel<<<nbRow, 256, 0, stream>>>(a, out, N);
}

// Round 2
// 1358.584 us; speedup vs baseline: 1.8486x; 1.8486x over previous
//
#include <hip/hip_runtime.h>
#include <math.h>

#define F_IN   500
#define H_DIM  64
#define C_DIM  40
#define K_STEPS 10
#define ALPHA  0.1f

typedef float vf4 __attribute__((ext_vector_type(4)));
typedef _Float16 hf;
typedef _Float16 h4 __attribute__((ext_vector_type(4)));

// ---------------------------------------------------------------------------
// Fused MLP GEMM: h0 = relu(x@W1+b1)@W2+b2, one 64-row tile per block.
// h0 written fp32 row-major; hA written fp16 row-major (propagation state).
// NOTE (next round): MfmaUtil=0, VALUBusy=35%, 1.6e7 LDS bank conflicts
// (8-way on transposed xs store: 4*LDA1 % 32 == 16) -> split-bf16 MFMA.
// ---------------------------------------------------------------------------
#define LDA1 68
__global__ __launch_bounds__(256) void mlp_gemm(
    const float* __restrict__ x, const float* __restrict__ W1,
    const float* __restrict__ b1, const float* __restrict__ W2,
    const float* __restrict__ b2, float* __restrict__ h0,
    hf* __restrict__ hA, int N)
{
    __shared__ float smem[64 * LDA1 * 2 + H_DIM * C_DIM];
    float* xs  = smem;
    float* ws  = smem + 64 * LDA1;
    float* w2s = smem + 2 * 64 * LDA1;

    const int t    = threadIdx.x;
    const int row0 = blockIdx.x * 64;
    const int tx   = t & 15;
    const int ty   = t >> 4;

    for (int i = t; i < H_DIM * C_DIM; i += 256) w2s[i] = W2[i];

    const float4 b1v = *(const float4*)&b1[tx * 4];

    float acc[4][4];
    #pragma unroll
    for (int i = 0; i < 4; ++i)
        #pragma unroll
        for (int j = 0; j < 4; ++j) acc[i][j] = 0.f;

    for (int k0 = 0; k0 < F_IN; k0 += 64) {
        __syncthreads();
        #pragma unroll
        for (int i = 0; i < 4; ++i) {
            int f  = t + i * 256;
            int r  = f >> 4;
            int c4 = (f & 15) << 2;
            int grow = row0 + r, gk = k0 + c4;
            float4 v = make_float4(0.f, 0.f, 0.f, 0.f);
            if (grow < N && gk < F_IN)
                v = *(const float4*)&x[(long long)grow * F_IN + gk];
            xs[(c4 + 0) * LDA1 + r] = v.x;
            xs[(c4 + 1) * LDA1 + r] = v.y;
            xs[(c4 + 2) * LDA1 + r] = v.z;
            xs[(c4 + 3) * LDA1 + r] = v.w;
        }
        #pragma unroll
        for (int i = 0; i < 4; ++i) {
            int f  = t + i * 256;
            int r  = f >> 4;
            int c4 = (f & 15) << 2;
            int gk = k0 + r;
            float4 v = make_float4(0.f, 0.f, 0.f, 0.f);
            if (gk < F_IN)
                v = *(const float4*)&W1[(long long)gk * H_DIM + c4];
            *(float4*)&ws[r * LDA1 + c4] = v;
        }
        __syncthreads();
        #pragma unroll 8
        for (int kk = 0; kk < 64; ++kk) {
            float4 a4 = *(const float4*)&xs[kk * LDA1 + ty * 4];
            float4 b4 = *(const float4*)&ws[kk * LDA1 + tx * 4];
            const float av[4] = {a4.x, a4.y, a4.z, a4.w};
            const float bv[4] = {b4.x, b4.y, b4.z, b4.w};
            #pragma unroll
            for (int i = 0; i < 4; ++i)
                #pragma unroll
                for (int j = 0; j < 4; ++j)
                    acc[i][j] = fmaf(av[i], bv[j], acc[i][j]);
        }
    }

    __syncthreads();
    #pragma unroll
    for (int i = 0; i < 4; ++i) {
        float4 hv;
        hv.x = fmaxf(acc[i][0] + b1v.x, 0.f);
        hv.y = fmaxf(acc[i][1] + b1v.y, 0.f);
        hv.z = fmaxf(acc[i][2] + b1v.z, 0.f);
        hv.w = fmaxf(acc[i][3] + b1v.w, 0.f);
        *(float4*)&xs[(ty * 4 + i) * LDA1 + tx * 4] = hv;
    }
    __syncthreads();

    for (int o = t; o < 64 * C_DIM; o += 256) {
        int r = o / C_DIM;
        int c = o - r * C_DIM;
        float s = b2[c];
        #pragma unroll 16
        for (int j = 0; j < H_DIM; ++j)
            s = fmaf(xs[r * LDA1 + j], w2s[j * C_DIM + c], s);
        int grow = row0 + r;
        if (grow < N) {
            long long idx = (long long)grow * C_DIM + c;
            h0[idx] = s;
            hA[idx] = (hf)s;
        }
    }
}

// ---------------------------------------------------------------------------
// Degree / normalization
// ---------------------------------------------------------------------------
__global__ void deg_init(float* __restrict__ deg, int N) {
    int i = blockIdx.x * 256 + threadIdx.x;
    if (i < N) deg[i] = 1.0f;               // self-loop
}

__global__ void deg_count(const int* __restrict__ dst, float* __restrict__ deg, int E) {
    int e = blockIdx.x * 256 + threadIdx.x;
    if (e < E) atomicAdd(&deg[dst[e]], 1.0f);
}

__global__ void dinv_kernel(float* __restrict__ deg, int* __restrict__ lengths, int N) {
    int i = blockIdx.x * 256 + threadIdx.x;
    if (i < N) {
        float d = deg[i];
        deg[i] = 1.0f / sqrtf(d);
        lengths[i] = (int)(d - 0.5f);
    }
}

// ---------------------------------------------------------------------------
// Exclusive prefix scan of row lengths -> row_ptr  (3-kernel block scan)
// ---------------------------------------------------------------------------
__global__ void scan1(const int* __restrict__ len, int* __restrict__ rp,
                      int* __restrict__ bsums, int N) {
    __shared__ int tmp[256];
    int tid = threadIdx.x;
    int gid = blockIdx.x * 256 + tid;
    int v = (gid < N) ? len[gid] : 0;
    tmp[tid] = v;
    __syncthreads();
    for (int off = 1; off < 256; off <<= 1) {
        int t = (tid >= off) ? tmp[tid - off] : 0;
        __syncthreads();
        tmp[tid] += t;
        __syncthreads();
    }
    if (gid < N) rp[gid] = tmp[tid] - v;
    if (tid == 255) bsums[blockIdx.x] = tmp[tid];
}

__global__ void scan2(int* __restrict__ bsums, int nb) {
    __shared__ int tmp[512];
    int tid = threadIdx.x;
    int v = (tid < nb) ? bsums[tid] : 0;
    tmp[tid] = v;
    __syncthreads();
    for (int off = 1; off < 512; off <<= 1) {
        int t = (tid >= off) ? tmp[tid - off] : 0;
        __syncthreads();
        tmp[tid] += t;
        __syncthreads();
    }
    if (tid < nb) bsums[tid] = tmp[tid] - v;
}

__global__ void scan3(int* __restrict__ rp, const int* __restrict__ bsums,
                      int* __restrict__ cursor, int N, int E) {
    int gid = blockIdx.x * 256 + threadIdx.x;
    if (gid < N) {
        int v = rp[gid] + bsums[blockIdx.x];
        rp[gid] = v;
        cursor[gid] = v;
    }
    if (gid == 0) rp[N] = E;
}

// ---------------------------------------------------------------------------
// CSR fill (direct scatter): earr[pos] = src | wq<<17,
// wq = round(dinv[src]*32767) (15-bit quantized, ~1e-4 rel err).
// ---------------------------------------------------------------------------
__global__ void csr_fill_direct(const int* __restrict__ src, const int* __restrict__ dst,
                                const float* __restrict__ dinv,
                                int* __restrict__ cursor, int* __restrict__ earr, int E) {
    int e = blockIdx.x * 256 + threadIdx.x;
    if (e >= E) return;
    int s = src[e];
    int d = dst[e];
    int pos = atomicAdd(&cursor[d], 1);
    unsigned wq = (unsigned)(dinv[s] * 32767.f + 0.5f);
    earr[pos] = (int)((unsigned)s | (wq << 17));
}

// ---------------------------------------------------------------------------
// PPR step v5: fp16 propagation state, full-row gather.
// Round-1 finding: prop is bound by per-CU line-request throughput
// (~284 M lines/s/CU; v3 fp32 = 3 lines/edge @135us, v4 blocked = 5 @220us,
// both same lines/s). fp16 row = 80 B -> exactly 2 lines/edge at any
// 80 B-stride phase -> predicted ~90 us/step.
// Wave layout (proven v3): 4 edge-groups x 16 lanes, 2-deep; lane q gathers
// h4 (8 B = 4 halfs) at slot qc=min(q,9); dup lanes coalesce.
// Accumulation/self/h0 all fp32; only stored state is fp16.
// ---------------------------------------------------------------------------
__global__ __launch_bounds__(256) void prop_h(
    const hf* __restrict__ hin, const float* __restrict__ h0,
    const float* __restrict__ dinv, const int* __restrict__ rp,
    const int* __restrict__ earr,
    hf* __restrict__ hout, int N)
{
    const int wave = threadIdx.x >> 6;
    const int lane = threadIdx.x & 63;
    const int row  = blockIdx.x * 4 + wave;
    if (row >= N) return;

    const int rs = rp[row];
    const int re = rp[row + 1];
    const float dr     = dinv[row];
    const float factor = (1.0f - ALPHA) * dr;
    const int e4 = lane >> 4;                 // edge subgroup 0..3
    const int q  = lane & 15;
    const int qc = (q < 10) ? q : 9;          // clamp; dup lanes coalesce

    const float invq = 1.0f / 32767.f;
    vf4 a0 = {0.f, 0.f, 0.f, 0.f};
    vf4 a1 = {0.f, 0.f, 0.f, 0.f};

    for (int base = rs; base < re; base += 64) {
        int ee = base + lane;
        int p = 0;
        if (ee < re) p = __builtin_nontemporal_load(&earr[ee]);  // padded: p=0 -> w=0
        int cnt = re - base; if (cnt > 64) cnt = 64;
        for (int i = 0; i < cnt; i += 8) {
            int p0 = __shfl(p, i + e4);
            int p1 = __shfl(p, i + 4 + e4);
            int   s0 = (int)((unsigned)p0 & 0x1FFFFu);
            int   s1 = (int)((unsigned)p1 & 0x1FFFFu);
            float w0 = (float)((unsigned)p0 >> 17) * invq;
            float w1 = (float)((unsigned)p1 >> 17) * invq;
            const h4 v0h = *(const h4*)(hin + (size_t)s0 * C_DIM + qc * 4);
            const h4 v1h = *(const h4*)(hin + (size_t)s1 * C_DIM + qc * 4);
            const vf4 v0 = __builtin_convertvector(v0h, vf4);
            const vf4 v1 = __builtin_convertvector(v1h, vf4);
            a0.x = fmaf(w0, v0.x, a0.x);
            a0.y = fmaf(w0, v0.y, a0.y);
            a0.z = fmaf(w0, v0.z, a0.z);
            a0.w = fmaf(w0, v0.w, a0.w);
            a1.x = fmaf(w1, v1.x, a1.x);
            a1.y = fmaf(w1, v1.y, a1.y);
            a1.z = fmaf(w1, v1.z, a1.z);
            a1.w = fmaf(w1, v1.w, a1.w);
        }
    }

    vf4 acc = a0 + a1;
    // reduce over the 4 edge-subgroups; channel-slot classes (q) stay separate
    acc.x += __shfl_xor(acc.x, 16);
    acc.y += __shfl_xor(acc.y, 16);
    acc.z += __shfl_xor(acc.z, 16);
    acc.w += __shfl_xor(acc.w, 16);
    acc.x += __shfl_xor(acc.x, 32);
    acc.y += __shfl_xor(acc.y, 32);
    acc.z += __shfl_xor(acc.z, 32);
    acc.w += __shfl_xor(acc.w, 32);

    if (lane < 10) {
        const size_t rbase = (size_t)row * C_DIM + lane * 4;
        const h4 hvh = *(const h4*)(hin + rbase);
        const vf4 hv = __builtin_convertvector(hvh, vf4);
        const float4 h0v = *(const float4*)&h0[rbase];
        vf4 o;
        o.x = fmaf(factor, acc.x + dr * hv.x, ALPHA * h0v.x);
        o.y = fmaf(factor, acc.y + dr * hv.y, ALPHA * h0v.y);
        o.z = fmaf(factor, acc.z + dr * hv.z, ALPHA * h0v.z);
        o.w = fmaf(factor, acc.w + dr * hv.w, ALPHA * h0v.w);
        h4 oh;
        oh.x = (hf)o.x; oh.y = (hf)o.y; oh.z = (hf)o.z; oh.w = (hf)o.w;
        *(h4*)(hout + rbase) = oh;
    }
}

// ---------------------------------------------------------------------------
// Row-wise log_softmax over 40 channels (wave per row), fp16 in, fp32 out
// ---------------------------------------------------------------------------
__global__ __launch_bounds__(256) void lsm_kernel(const hf* __restrict__ hin,
                                                  float* __restrict__ out, int N) {
    const int wave = threadIdx.x >> 6;
    const int lane = threadIdx.x & 63;
    const int row  = blockIdx.x * 4 + wave;
    if (row >= N) return;

    float v = (lane < C_DIM) ? (float)hin[(size_t)row * C_DIM + lane] : -INFINITY;
    float m = v;
    for (int off = 32; off; off >>= 1) m = fmaxf(m, __shfl_xor(m, off));
    float e = (lane < C_DIM) ? expf(v - m) : 0.f;
    float s = e;
    for (int off = 32; off; off >>= 1) s += __shfl_xor(s, off);
    if (lane < C_DIM) out[(long long)row * C_DIM + lane] = (v - m) - logf(s);
}

// ---------------------------------------------------------------------------
extern "C" void kernel_launch(void* const* d_in, const int* in_sizes, int n_in,
                              void* d_out, int out_size, void* d_ws, size_t ws_size,
                              hipStream_t stream) {
    const float* x  = (const float*)d_in[0];
    const float* W1 = (const float*)d_in[1];
    const float* b1 = (const float*)d_in[2];
    const float* W2 = (const float*)d_in[3];
    const float* b2 = (const float*)d_in[4];
    const int* ei = (const int*)d_in[5];   // int32 per harness contract

    const int N = in_sizes[0] / F_IN;          // 100000
    const int E = in_sizes[5] / 2;             // 3200000
    const int* src = ei;
    const int* dst = ei + E;
    float* out = (float*)d_out;

    char* w = (char*)d_ws;
    float* h0    = (float*)w;  w += (size_t)N * C_DIM * 4;   // 16 MB fp32
    hf*    hA    = (hf*)w;     w += (size_t)N * C_DIM * 2;   // 8 MB fp16 ping
    hf*    hB    = (hf*)w;     w += (size_t)N * C_DIM * 2;   // 8 MB fp16 pong
    float* dinv  = (float*)w;  w += (size_t)N * 4;           // deg -> dinv in place
    int*   rp    = (int*)w;    w += (size_t)(N + 1) * 4;
    int*   cursor= (int*)w;    w += (size_t)N * 4;           // lengths, then cursor
    int*   bsums = (int*)w;    w += (size_t)512 * 4;
    int*   earr  = (int*)w;    w += (size_t)E * 4;           // 12.8 MB packed edges

    const int nbN = (N + 255) / 256;
    const int nbE = (E + 255) / 256;
    const int nbRow = (N + 3) / 4;
    const int nbGemm = (N + 63) / 64;

    mlp_gemm<<<nbGemm, 256, 0, stream>>>(x, W1, b1, W2, b2, h0, hA, N);

    deg_init <<<nbN, 256, 0, stream>>>(dinv, N);
    deg_count<<<nbE, 256, 0, stream>>>(dst, dinv, E);
    dinv_kernel<<<nbN, 256, 0, stream>>>(dinv, cursor, N);

    scan1<<<nbN, 256, 0, stream>>>(cursor, rp, bsums, N);
    scan2<<<1, 512, 0, stream>>>(bsums, nbN);
    scan3<<<nbN, 256, 0, stream>>>(rp, bsums, cursor, N, E);

    csr_fill_direct<<<nbE, 256, 0, stream>>>(src, dst, dinv, cursor, earr, E);

    // ping-pong hA <-> hB; after 10 steps result is back in hA
    hf* a = hA; hf* b = hB;
    for (int k = 0; k < K_STEPS; ++k) {
        prop_h<<<nbRow, 256, 0, stream>>>(a, h0, dinv, rp, earr, b, N);
        hf* t = a; a = b; b = t;
    }

    lsm_kernel<<<nbRow, 256, 0, stream>>>(a, out, N);
}